// Round 1
// baseline (4863.356 us; speedup 1.0000x reference)
//
#include <hip/hip_runtime.h>
#include <math.h>

#define T_STEPS 2048
#define BATCH   16
#define DIM     1024
#define NSTATE  64
static constexpr float EPS = 1e-6f;

// proj row layout per (t,b): [0:64) k_norm | [64:128) v | [128:192) q | [192:256) g

__global__ __launch_bounds__(256) void proj_kernel(
    const float* __restrict__ x,    // [T*B][DIM]
    const float* __restrict__ Wk,   // [64][DIM]
    const float* __restrict__ Wv,
    const float* __restrict__ Wq,
    const float* __restrict__ Wb,
    const float* __restrict__ bb,   // [64]
    float* __restrict__ proj)       // [T*B][256]
{
    __shared__ float4 xs4[DIM / 4];
    const int tb  = blockIdx.x;     // t*B + b
    const int tid = threadIdx.x;

    const float4* xrow4 = (const float4*)(x + (size_t)tb * DIM);
    xs4[tid] = xrow4[tid];          // 256 threads x float4 = 1024 floats
    __syncthreads();

    const int f = tid >> 6;         // 0:k 1:v 2:q 3:beta  (each = one full wave)
    const int n = tid & 63;
    const float* W = (f == 0 ? Wk : f == 1 ? Wv : f == 2 ? Wq : Wb) + (size_t)n * DIM;
    const float4* W4 = (const float4*)W;

    float acc = 0.f;
    #pragma unroll 4
    for (int d = 0; d < DIM / 4; ++d) {
        float4 w  = W4[d];
        float4 xv = xs4[d];
        acc = fmaf(w.x, xv.x, acc);
        acc = fmaf(w.y, xv.y, acc);
        acc = fmaf(w.z, xv.z, acc);
        acc = fmaf(w.w, xv.w, acc);
    }

    float val = acc;
    if (f == 0) {
        // k-normalization: threads 0..63 are exactly wave 0 -> full-wave reduce
        float s = acc * acc;
        s += __shfl_xor(s, 1);  s += __shfl_xor(s, 2);  s += __shfl_xor(s, 4);
        s += __shfl_xor(s, 8);  s += __shfl_xor(s, 16); s += __shfl_xor(s, 32);
        val = acc / (sqrtf(s) + EPS);
    } else if (f == 3) {
        float z = acc + bb[n];
        val = 1.f / (1.f + __expf(-z));
    }
    proj[(size_t)tb * 256 + tid] = val;
}

// One row (b,i) of S is owned by a 16-lane group; each lane holds 4 columns.
// Wave-synchronous: reductions are 4-deep shfl_xor chains, no barriers/LDS.
__global__ __launch_bounds__(256) void scan_kernel(
    const float* __restrict__ proj,  // [T*B][256]
    const float* __restrict__ S0,    // [B][64][64]
    float* __restrict__ out,         // [T][B][64]
    float* __restrict__ Sfin)        // [B][64][64]
{
    const int tid = threadIdx.x;
    const int l   = tid & 15;                // lane within row-group
    const int grp = tid >> 4;                // row-group within block (0..15)
    const int R   = blockIdx.x * 16 + grp;   // global row id, 0..1023
    const int b   = R >> 6;
    const int i   = R & 63;
    const int c0  = l * 4;                   // column base

    const size_t srow = ((size_t)(b * 64 + i)) * 64 + c0;
    float4 S = *(const float4*)(S0 + srow);

    const float* pb = proj + (size_t)b * 256;
    for (int t = 0; t < T_STEPS; ++t) {
        const float* p = pb + (size_t)t * (BATCH * 256);
        float4 kn = *(const float4*)(p + c0);
        float4 q  = *(const float4*)(p + 128 + c0);
        float  v  = p[64  + i];
        float  g  = p[192 + i];

        // retrieved = S_row . kn   (partial + 16-lane reduce)
        float r = S.x * kn.x + S.y * kn.y + S.z * kn.z + S.w * kn.w;
        r += __shfl_xor(r, 1); r += __shfl_xor(r, 2);
        r += __shfl_xor(r, 4); r += __shfl_xor(r, 8);

        float d = v - r;

        S.x = fmaf(d, kn.x, g * S.x);
        S.y = fmaf(d, kn.y, g * S.y);
        S.z = fmaf(d, kn.z, g * S.z);
        S.w = fmaf(d, kn.w, g * S.w);

        float sq = S.x * q.x + S.y * q.y + S.z * q.z + S.w * q.w;
        sq += __shfl_xor(sq, 1); sq += __shfl_xor(sq, 2);
        sq += __shfl_xor(sq, 4); sq += __shfl_xor(sq, 8);

        if (l == 0) {
            float sig = 1.f / (1.f + __expf(-sq));
            out[((size_t)t * BATCH + b) * 64 + i] = sq * sq * sig;
        }
    }
    *(float4*)(Sfin + srow) = S;
}

extern "C" void kernel_launch(void* const* d_in, const int* in_sizes, int n_in,
                              void* d_out, int out_size, void* d_ws, size_t ws_size,
                              hipStream_t stream) {
    const float* x  = (const float*)d_in[0];
    const float* S0 = (const float*)d_in[1];
    const float* Wk = (const float*)d_in[2];
    const float* Wv = (const float*)d_in[3];
    const float* Wq = (const float*)d_in[4];
    const float* Wb = (const float*)d_in[5];
    const float* bb = (const float*)d_in[6];

    float* out  = (float*)d_out;                               // [T][B][64]
    float* Sfin = out + (size_t)T_STEPS * BATCH * NSTATE;      // [B][64][64]
    float* proj = (float*)d_ws;                                // [T*B][256], 8.4 MB

    proj_kernel<<<T_STEPS * BATCH, 256, 0, stream>>>(x, Wk, Wv, Wq, Wb, bb, proj);
    scan_kernel<<<(BATCH * NSTATE) / 16, 256, 0, stream>>>(proj, S0, out, Sfin);
}

// Round 2
// 818.186 us; speedup vs baseline: 5.9441x; 5.9441x over previous
//
#include <hip/hip_runtime.h>
#include <math.h>

#define T_STEPS 2048
#define BATCH   16
#define DIM     1024
#define NSTATE  64
#define NFIELD  256                      // per (t,b): [k_norm|v|q|g] x 64
#define PROJ_TSTRIDE (BATCH * NFIELD)    // 4096 floats per t
static constexpr float EPS = 1e-6f;

// ============================ projection GEMM ============================
// proj[M=32768][256] = x[M][1024] @ B[1024][256],  B[k][n] = W_{n>>6}[n&63][k]
// BM=64 rows/block, BN=256 (all fields), BK=16. 256 threads.
// Thread (tx=tid&15, ty=tid>>4) owns 4 M-rows x 16 N-cols, where its 16 cols
// are n = 64*w + 4*tx + e  (w=field 0..3, e=0..3)  -> bank-conflict-free frag
// reads AND field-aligned epilogue (w==0 is the k-field, w==3 the gate).

#define BM   64
#define BK   16
#define APAD 68    // As[BK][APAD]  (float4 reads stay 16B aligned, 2-way max)
#define BPAD 260   // Bs[BK][BPAD]  (4k+4tx bank pattern -> 2-way max)

__global__ __launch_bounds__(256, 2) void proj_kernel(
    const float* __restrict__ x,
    const float* __restrict__ Wk, const float* __restrict__ Wv,
    const float* __restrict__ Wq, const float* __restrict__ Wb,
    const float* __restrict__ bb,
    float* __restrict__ proj)
{
    __shared__ float As[BK][APAD];
    __shared__ float Bs[BK][BPAD];

    const int tid = threadIdx.x;
    const int tx = tid & 15, ty = tid >> 4;
    const int ms = tid >> 2;          // staging: row within tile (0..63)
    const int js = tid & 3;           // staging: k-quad (0..3)
    const size_t mbase = (size_t)blockIdx.x * BM;
    const float* xrow = x + (mbase + ms) * DIM;
    const int nf = tid >> 6, n63 = tid & 63;   // staging: one W row per thread
    const float* Wrow = (nf == 0 ? Wk : nf == 1 ? Wv : nf == 2 ? Wq : Wb)
                        + (size_t)n63 * DIM;

    float acc[4][16] = {};            // [mm][w*4+e]

    // prefetch k-chunk 0 into registers
    float4 xa = *(const float4*)(xrow + 4 * js);
    float4 w0 = *(const float4*)(Wrow + 0);
    float4 w1 = *(const float4*)(Wrow + 4);
    float4 w2 = *(const float4*)(Wrow + 8);
    float4 w3 = *(const float4*)(Wrow + 12);

    for (int k0 = 0; k0 < DIM; k0 += BK) {
        __syncthreads();              // previous chunk's LDS reads done
        As[4 * js + 0][ms] = xa.x;
        As[4 * js + 1][ms] = xa.y;
        As[4 * js + 2][ms] = xa.z;
        As[4 * js + 3][ms] = xa.w;
        Bs[ 0][tid] = w0.x; Bs[ 1][tid] = w0.y; Bs[ 2][tid] = w0.z; Bs[ 3][tid] = w0.w;
        Bs[ 4][tid] = w1.x; Bs[ 5][tid] = w1.y; Bs[ 6][tid] = w1.z; Bs[ 7][tid] = w1.w;
        Bs[ 8][tid] = w2.x; Bs[ 9][tid] = w2.y; Bs[10][tid] = w2.z; Bs[11][tid] = w2.w;
        Bs[12][tid] = w3.x; Bs[13][tid] = w3.y; Bs[14][tid] = w3.z; Bs[15][tid] = w3.w;
        __syncthreads();

        if (k0 + BK < DIM) {          // prefetch next chunk (hidden under compute)
            const int kn = k0 + BK;
            xa = *(const float4*)(xrow + kn + 4 * js);
            w0 = *(const float4*)(Wrow + kn + 0);
            w1 = *(const float4*)(Wrow + kn + 4);
            w2 = *(const float4*)(Wrow + kn + 8);
            w3 = *(const float4*)(Wrow + kn + 12);
        }

        #pragma unroll
        for (int k = 0; k < BK; ++k) {
            float a[4];
            { float4 t = *(const float4*)(&As[k][ty * 4]);
              a[0] = t.x; a[1] = t.y; a[2] = t.z; a[3] = t.w; }
            float bfr[16];
            #pragma unroll
            for (int w = 0; w < 4; ++w) {
                float4 t = *(const float4*)(&Bs[k][64 * w + 4 * tx]);
                bfr[4 * w + 0] = t.x; bfr[4 * w + 1] = t.y;
                bfr[4 * w + 2] = t.z; bfr[4 * w + 3] = t.w;
            }
            #pragma unroll
            for (int mm = 0; mm < 4; ++mm)
                #pragma unroll
                for (int nn = 0; nn < 16; ++nn)
                    acc[mm][nn] = fmaf(a[mm], bfr[nn], acc[mm][nn]);
        }
    }

    // -------- epilogue: k-norm (w=0) and sigmoid gate (w=3), in-register ----
    #pragma unroll
    for (int mm = 0; mm < 4; ++mm) {
        float s = acc[mm][0] * acc[mm][0] + acc[mm][1] * acc[mm][1]
                + acc[mm][2] * acc[mm][2] + acc[mm][3] * acc[mm][3];
        s += __shfl_xor(s, 1); s += __shfl_xor(s, 2);
        s += __shfl_xor(s, 4); s += __shfl_xor(s, 8);
        const float sc = 1.f / (sqrtf(s) + EPS);
        acc[mm][0] *= sc; acc[mm][1] *= sc; acc[mm][2] *= sc; acc[mm][3] *= sc;
    }
    const float bb0 = bb[4 * tx + 0], bb1 = bb[4 * tx + 1];
    const float bb2 = bb[4 * tx + 2], bb3 = bb[4 * tx + 3];
    #pragma unroll
    for (int mm = 0; mm < 4; ++mm) {
        acc[mm][12] = 1.f / (1.f + __expf(-(acc[mm][12] + bb0)));
        acc[mm][13] = 1.f / (1.f + __expf(-(acc[mm][13] + bb1)));
        acc[mm][14] = 1.f / (1.f + __expf(-(acc[mm][14] + bb2)));
        acc[mm][15] = 1.f / (1.f + __expf(-(acc[mm][15] + bb3)));
    }
    #pragma unroll
    for (int mm = 0; mm < 4; ++mm) {
        float* dst = proj + (mbase + ty * 4 + mm) * NFIELD;
        *(float4*)(dst +   0 + 4 * tx) = make_float4(acc[mm][ 0], acc[mm][ 1], acc[mm][ 2], acc[mm][ 3]);
        *(float4*)(dst +  64 + 4 * tx) = make_float4(acc[mm][ 4], acc[mm][ 5], acc[mm][ 6], acc[mm][ 7]);
        *(float4*)(dst + 128 + 4 * tx) = make_float4(acc[mm][ 8], acc[mm][ 9], acc[mm][10], acc[mm][11]);
        *(float4*)(dst + 192 + 4 * tx) = make_float4(acc[mm][12], acc[mm][13], acc[mm][14], acc[mm][15]);
    }
}

// ============================ sequential scan ============================
// 1024 independent row-recurrences; 16 lanes per row (4 cols each).
// Proj data staged through double-buffered LDS in 64-step chunks; next chunk's
// global loads issue BEFORE the current chunk's compute (latency hidden).
// 16-lane reductions via DPP row_ror adds (VALU-latency, no LDS round-trip).

template <int CTRL>
__device__ __forceinline__ float dpp_add(float x) {
    int yi = __builtin_amdgcn_update_dpp(0, __float_as_int(x), CTRL, 0xF, 0xF, true);
    return x + __int_as_float(yi);
}
__device__ __forceinline__ float reduce16(float x) {
    x = dpp_add<0x121>(x);   // row_ror:1
    x = dpp_add<0x122>(x);   // row_ror:2
    x = dpp_add<0x124>(x);   // row_ror:4
    x = dpp_add<0x128>(x);   // row_ror:8
    return x;                // all 16 lanes hold the row sum
}

#define CH 64   // steps per LDS chunk

__global__ __launch_bounds__(256, 1) void scan_kernel(
    const float* __restrict__ proj,  // [T][B][256]
    const float* __restrict__ S0,    // [B][64][64]
    float* __restrict__ out,         // [T][B][64]
    float* __restrict__ Sfin)        // [B][64][64]
{
    __shared__ float buf[2][CH * NFIELD];   // 2 x 64KB

    const int tid = threadIdx.x;
    const int l   = tid & 15;
    const int grp = tid >> 4;
    const int b   = blockIdx.x >> 2;
    const int i   = (blockIdx.x & 3) * 16 + grp;
    const int c0  = l * 4;

    const size_t srow = ((size_t)(b * 64 + i)) * 64 + c0;
    float4 S = *(const float4*)(S0 + srow);

    const float* pb = proj + (size_t)b * NFIELD;
    float4 hold[16];

    // load chunk 0
    #pragma unroll
    for (int it = 0; it < 16; ++it) {
        const int flat = it * 1024 + tid * 4;
        const int s = flat >> 8, f = flat & 255;
        hold[it] = *(const float4*)(pb + (size_t)s * PROJ_TSTRIDE + f);
    }
    #pragma unroll
    for (int it = 0; it < 16; ++it)
        *(float4*)(&buf[0][it * 1024 + tid * 4]) = hold[it];
    __syncthreads();

    for (int c = 0; c < T_STEPS / CH; ++c) {
        const bool more = (c + 1 < T_STEPS / CH);
        if (more) {   // issue next chunk's global loads now; consumed after compute
            const float* src = pb + (size_t)(c + 1) * CH * PROJ_TSTRIDE;
            #pragma unroll
            for (int it = 0; it < 16; ++it) {
                const int flat = it * 1024 + tid * 4;
                const int s = flat >> 8, f = flat & 255;
                hold[it] = *(const float4*)(src + (size_t)s * PROJ_TSTRIDE + f);
            }
        }

        const float* B0 = &buf[c & 1][0];
        #pragma unroll 4
        for (int s = 0; s < CH; ++s) {
            const float* P = B0 + s * NFIELD;
            float4 kn = *(const float4*)(P + c0);
            float4 q  = *(const float4*)(P + 128 + c0);
            float  v  = P[64 + i];
            float  g  = P[192 + i];

            float r = S.x * kn.x + S.y * kn.y + S.z * kn.z + S.w * kn.w;
            r = reduce16(r);
            const float d = v - r;

            S.x = fmaf(d, kn.x, g * S.x);
            S.y = fmaf(d, kn.y, g * S.y);
            S.z = fmaf(d, kn.z, g * S.z);
            S.w = fmaf(d, kn.w, g * S.w);

            float sq = S.x * q.x + S.y * q.y + S.z * q.z + S.w * q.w;
            sq = reduce16(sq);

            if (l == 0) {
                const float sig = 1.f / (1.f + __expf(-sq));
                out[((size_t)(c * CH + s) * BATCH + b) * 64 + i] = sq * sq * sig;
            }
        }

        if (more) {
            float* dst = &buf[(c + 1) & 1][0];
            #pragma unroll
            for (int it = 0; it < 16; ++it)
                *(float4*)(dst + it * 1024 + tid * 4) = hold[it];
        }
        __syncthreads();
    }

    *(float4*)(Sfin + srow) = S;
}

// ================================ launch ================================
extern "C" void kernel_launch(void* const* d_in, const int* in_sizes, int n_in,
                              void* d_out, int out_size, void* d_ws, size_t ws_size,
                              hipStream_t stream) {
    const float* x  = (const float*)d_in[0];
    const float* S0 = (const float*)d_in[1];
    const float* Wk = (const float*)d_in[2];
    const float* Wv = (const float*)d_in[3];
    const float* Wq = (const float*)d_in[4];
    const float* Wb = (const float*)d_in[5];
    const float* bb = (const float*)d_in[6];

    float* out  = (float*)d_out;                               // [T][B][64]
    float* Sfin = out + (size_t)T_STEPS * BATCH * NSTATE;      // [B][64][64]
    float* proj = (float*)d_ws;                                // [T*B][256] = 33.5 MB

    proj_kernel<<<(T_STEPS * BATCH) / BM, 256, 0, stream>>>(x, Wk, Wv, Wq, Wb, bb, proj);
    scan_kernel<<<(BATCH * NSTATE) / 16, 256, 0, stream>>>(proj, S0, out, Sfin);
}

// Round 3
// 669.756 us; speedup vs baseline: 7.2614x; 1.2216x over previous
//
#include <hip/hip_runtime.h>
#include <math.h>

#define T_STEPS 2048
#define BATCH   16
#define DIM     1024
#define NSTATE  64
#define NFIELD  256                      // per (t,b): [k_norm|v|q|g] x 64
#define PROJ_TSTRIDE (BATCH * NFIELD)    // 4096 floats per t
static constexpr float EPS = 1e-6f;

// ============================ projection GEMM ============================
// (unchanged from R1 — L2-traffic-fixed tiled fp32 GEMM, ~340 us)

#define BM   64
#define BK   16
#define APAD 68
#define BPAD 260

__global__ __launch_bounds__(256, 2) void proj_kernel(
    const float* __restrict__ x,
    const float* __restrict__ Wk, const float* __restrict__ Wv,
    const float* __restrict__ Wq, const float* __restrict__ Wb,
    const float* __restrict__ bb,
    float* __restrict__ proj)
{
    __shared__ float As[BK][APAD];
    __shared__ float Bs[BK][BPAD];

    const int tid = threadIdx.x;
    const int tx = tid & 15, ty = tid >> 4;
    const int ms = tid >> 2;
    const int js = tid & 3;
    const size_t mbase = (size_t)blockIdx.x * BM;
    const float* xrow = x + (mbase + ms) * DIM;
    const int nf = tid >> 6, n63 = tid & 63;
    const float* Wrow = (nf == 0 ? Wk : nf == 1 ? Wv : nf == 2 ? Wq : Wb)
                        + (size_t)n63 * DIM;

    float acc[4][16] = {};

    float4 xa = *(const float4*)(xrow + 4 * js);
    float4 w0 = *(const float4*)(Wrow + 0);
    float4 w1 = *(const float4*)(Wrow + 4);
    float4 w2 = *(const float4*)(Wrow + 8);
    float4 w3 = *(const float4*)(Wrow + 12);

    for (int k0 = 0; k0 < DIM; k0 += BK) {
        __syncthreads();
        As[4 * js + 0][ms] = xa.x;
        As[4 * js + 1][ms] = xa.y;
        As[4 * js + 2][ms] = xa.z;
        As[4 * js + 3][ms] = xa.w;
        Bs[ 0][tid] = w0.x; Bs[ 1][tid] = w0.y; Bs[ 2][tid] = w0.z; Bs[ 3][tid] = w0.w;
        Bs[ 4][tid] = w1.x; Bs[ 5][tid] = w1.y; Bs[ 6][tid] = w1.z; Bs[ 7][tid] = w1.w;
        Bs[ 8][tid] = w2.x; Bs[ 9][tid] = w2.y; Bs[10][tid] = w2.z; Bs[11][tid] = w2.w;
        Bs[12][tid] = w3.x; Bs[13][tid] = w3.y; Bs[14][tid] = w3.z; Bs[15][tid] = w3.w;
        __syncthreads();

        if (k0 + BK < DIM) {
            const int kn = k0 + BK;
            xa = *(const float4*)(xrow + kn + 4 * js);
            w0 = *(const float4*)(Wrow + kn + 0);
            w1 = *(const float4*)(Wrow + kn + 4);
            w2 = *(const float4*)(Wrow + kn + 8);
            w3 = *(const float4*)(Wrow + kn + 12);
        }

        #pragma unroll
        for (int k = 0; k < BK; ++k) {
            float a[4];
            { float4 t = *(const float4*)(&As[k][ty * 4]);
              a[0] = t.x; a[1] = t.y; a[2] = t.z; a[3] = t.w; }
            float bfr[16];
            #pragma unroll
            for (int w = 0; w < 4; ++w) {
                float4 t = *(const float4*)(&Bs[k][64 * w + 4 * tx]);
                bfr[4 * w + 0] = t.x; bfr[4 * w + 1] = t.y;
                bfr[4 * w + 2] = t.z; bfr[4 * w + 3] = t.w;
            }
            #pragma unroll
            for (int mm = 0; mm < 4; ++mm)
                #pragma unroll
                for (int nn = 0; nn < 16; ++nn)
                    acc[mm][nn] = fmaf(a[mm], bfr[nn], acc[mm][nn]);
        }
    }

    #pragma unroll
    for (int mm = 0; mm < 4; ++mm) {
        float s = acc[mm][0] * acc[mm][0] + acc[mm][1] * acc[mm][1]
                + acc[mm][2] * acc[mm][2] + acc[mm][3] * acc[mm][3];
        s += __shfl_xor(s, 1); s += __shfl_xor(s, 2);
        s += __shfl_xor(s, 4); s += __shfl_xor(s, 8);
        const float sc = 1.f / (sqrtf(s) + EPS);
        acc[mm][0] *= sc; acc[mm][1] *= sc; acc[mm][2] *= sc; acc[mm][3] *= sc;
    }
    const float bb0 = bb[4 * tx + 0], bb1 = bb[4 * tx + 1];
    const float bb2 = bb[4 * tx + 2], bb3 = bb[4 * tx + 3];
    #pragma unroll
    for (int mm = 0; mm < 4; ++mm) {
        acc[mm][12] = 1.f / (1.f + __expf(-(acc[mm][12] + bb0)));
        acc[mm][13] = 1.f / (1.f + __expf(-(acc[mm][13] + bb1)));
        acc[mm][14] = 1.f / (1.f + __expf(-(acc[mm][14] + bb2)));
        acc[mm][15] = 1.f / (1.f + __expf(-(acc[mm][15] + bb3)));
    }
    #pragma unroll
    for (int mm = 0; mm < 4; ++mm) {
        float* dst = proj + (mbase + ty * 4 + mm) * NFIELD;
        *(float4*)(dst +   0 + 4 * tx) = make_float4(acc[mm][ 0], acc[mm][ 1], acc[mm][ 2], acc[mm][ 3]);
        *(float4*)(dst +  64 + 4 * tx) = make_float4(acc[mm][ 4], acc[mm][ 5], acc[mm][ 6], acc[mm][ 7]);
        *(float4*)(dst + 128 + 4 * tx) = make_float4(acc[mm][ 8], acc[mm][ 9], acc[mm][10], acc[mm][11]);
        *(float4*)(dst + 192 + 4 * tx) = make_float4(acc[mm][12], acc[mm][13], acc[mm][14], acc[mm][15]);
    }
}

// ============================ sequential scan v3 ============================
// 128 blocks x 128 thr: block = (batch b, 8 rows i0..i0+7); 16 lanes/row.
// LDS double-buffer holds only kn+q (shared across waves) + per-row v,g.
// Inner 64-step loop FULLY UNROLLED: depth-2 LDS->reg pipeline (3 rotating
// slots), branchless silu output latched per-lane, burst-stored every 16 steps.

template <int CTRL>
__device__ __forceinline__ float dpp_add(float x) {
    int yi = __builtin_amdgcn_update_dpp(0, __float_as_int(x), CTRL, 0xF, 0xF, true);
    return x + __int_as_float(yi);
}
__device__ __forceinline__ float reduce16(float x) {
    x = dpp_add<0x121>(x);   // row_ror:1
    x = dpp_add<0x122>(x);   // row_ror:2
    x = dpp_add<0x124>(x);   // row_ror:4
    x = dpp_add<0x128>(x);   // row_ror:8
    return x;                // all 16 lanes hold the group sum
}

#define CH 64
#define NCHUNK (T_STEPS / CH)

__global__ __launch_bounds__(128) void scan_kernel(
    const float* __restrict__ proj,  // [T][B][256]
    const float* __restrict__ S0,    // [B][64][64]
    float* __restrict__ out,         // [T][B][64]
    float* __restrict__ Sfin)        // [B][64][64]
{
    __shared__ float KQ[2][CH][128];   // [s][0:64)=kn, [64:128)=q   (64 KB)
    __shared__ float VG[2][CH][16];    // [s][0:8)=v rows, [8:16)=g  ( 8 KB)

    const int tid = threadIdx.x;          // 0..127
    const int l   = tid & 15;
    const int grp = tid >> 4;             // 0..7 -> row within block
    const int b   = blockIdx.x >> 3;
    const int i0  = (blockIdx.x & 7) * 8;
    const int i   = i0 + grp;
    const int c0  = l * 4;

    const size_t srow = ((size_t)(b * 64 + i)) * 64 + c0;
    float4 S = *(const float4*)(S0 + srow);

    const float* pb = proj + (size_t)b * NFIELD;

    // ---- staging maps (constant per thread) ----
    // KQ: 16 iters, flat = it*512 + tid*4 -> s = it*4 + (tid>>5), f = (tid*4)&127
    const int s_kq = tid >> 5;
    const int fraw = (tid * 4) & 127;
    const int fmap = (fraw < 64) ? fraw : fraw + 64;   // kn field f | q field 128+(f-64)
    // VG: 2 iters, flat = it*512 + tid*4 -> s = it*32 + (tid>>2), r = (tid&3)*4
    const int svg0 = tid >> 2;
    const int rvg  = (tid & 3) * 4;
    const int fvg  = (rvg < 8) ? (64 + i0 + rvg) : (192 + i0 + rvg - 8);

    float4 hold[18];

    auto load_chunk = [&](int c) {
        const float* cbase = pb + (size_t)c * CH * PROJ_TSTRIDE;
        #pragma unroll
        for (int it = 0; it < 16; ++it)
            hold[it] = *(const float4*)(cbase + (size_t)(it * 4 + s_kq) * PROJ_TSTRIDE + fmap);
        #pragma unroll
        for (int it = 0; it < 2; ++it)
            hold[16 + it] = *(const float4*)(cbase + (size_t)(it * 32 + svg0) * PROJ_TSTRIDE + fvg);
    };
    auto store_chunk = [&](int nb) {
        #pragma unroll
        for (int it = 0; it < 16; ++it)
            *(float4*)(&KQ[nb][it * 4 + s_kq][fraw]) = hold[it];
        #pragma unroll
        for (int it = 0; it < 2; ++it)
            *(float4*)(&VG[nb][it * 32 + svg0][rvg]) = hold[16 + it];
    };

    load_chunk(0);
    store_chunk(0);
    __syncthreads();

    float4 kn_s[3], q_s[3];
    float  v_s[3], g_s[3];
    #pragma unroll
    for (int j = 0; j < 2; ++j) {
        kn_s[j] = *(const float4*)(&KQ[0][j][c0]);
        q_s[j]  = *(const float4*)(&KQ[0][j][64 + c0]);
        v_s[j]  = VG[0][j][grp];
        g_s[j]  = VG[0][j][8 + grp];
    }

    float osel = 0.f;

    for (int c = 0; c < NCHUNK; ++c) {
        const int cb = c & 1;
        const bool more = (c + 1 < NCHUNK);
        if (more) load_chunk(c + 1);   // global loads in flight across the chunk

        #pragma unroll
        for (int s = 0; s < CH; ++s) {
            const int j  = s % 3;
            const int jn = (s + 2) % 3;
            if (s + 2 < CH) {          // issue LDS reads 2 steps ahead
                kn_s[jn] = *(const float4*)(&KQ[cb][s + 2][c0]);
                q_s[jn]  = *(const float4*)(&KQ[cb][s + 2][64 + c0]);
                v_s[jn]  = VG[cb][s + 2][grp];
                g_s[jn]  = VG[cb][s + 2][8 + grp];
            }
            const float4 kn = kn_s[j], q = q_s[j];
            const float  v  = v_s[j],  g = g_s[j];

            // retrieved = S_row . kn  (tree dot + 16-lane DPP reduce)
            float t0 = S.x * kn.x; t0 = fmaf(S.y, kn.y, t0);
            float t1 = S.z * kn.z; t1 = fmaf(S.w, kn.w, t1);
            const float r = reduce16(t0 + t1);

            // g*S is independent of r -> overlaps the reduce
            const float gx = g * S.x, gy = g * S.y, gz = g * S.z, gw = g * S.w;
            const float d = v - r;
            S.x = fmaf(d, kn.x, gx);
            S.y = fmaf(d, kn.y, gy);
            S.z = fmaf(d, kn.z, gz);
            S.w = fmaf(d, kn.w, gw);

            float u0 = S.x * q.x; u0 = fmaf(S.y, q.y, u0);
            float u1 = S.z * q.z; u1 = fmaf(S.w, q.w, u1);
            const float sq = reduce16(u0 + u1);

            const float sig = 1.f / (1.f + __expf(-sq));
            const float ov  = sq * sq * sig;
            osel = ((s & 15) == l) ? ov : osel;     // cndmask, no branch

            if ((s & 15) == 15) {                   // compile-time under unroll
                const int tbase = c * CH + (s - 15);
                out[((size_t)(tbase + l) * BATCH + b) * 64 + i] = osel;
            }
        }

        if (more) {
            const int nb = (c + 1) & 1;
            store_chunk(nb);
            __syncthreads();
            #pragma unroll
            for (int j2 = 0; j2 < 2; ++j2) {
                kn_s[j2] = *(const float4*)(&KQ[nb][j2][c0]);
                q_s[j2]  = *(const float4*)(&KQ[nb][j2][64 + c0]);
                v_s[j2]  = VG[nb][j2][grp];
                g_s[j2]  = VG[nb][j2][8 + grp];
            }
        }
    }

    *(float4*)(Sfin + srow) = S;
}

// ================================ launch ================================
extern "C" void kernel_launch(void* const* d_in, const int* in_sizes, int n_in,
                              void* d_out, int out_size, void* d_ws, size_t ws_size,
                              hipStream_t stream) {
    const float* x  = (const float*)d_in[0];
    const float* S0 = (const float*)d_in[1];
    const float* Wk = (const float*)d_in[2];
    const float* Wv = (const float*)d_in[3];
    const float* Wq = (const float*)d_in[4];
    const float* Wb = (const float*)d_in[5];
    const float* bb = (const float*)d_in[6];

    float* out  = (float*)d_out;                               // [T][B][64]
    float* Sfin = out + (size_t)T_STEPS * BATCH * NSTATE;      // [B][64][64]
    float* proj = (float*)d_ws;                                // [T*B][256] = 33.5 MB

    proj_kernel<<<(T_STEPS * BATCH) / BM, 256, 0, stream>>>(x, Wk, Wv, Wq, Wb, bb, proj);
    scan_kernel<<<(BATCH * NSTATE) / 8, 128, 0, stream>>>(proj, S0, out, Sfin);
}

// Round 4
// 625.403 us; speedup vs baseline: 7.7764x; 1.0709x over previous
//
#include <hip/hip_runtime.h>
#include <math.h>

#define T_STEPS 2048
#define BATCH   16
#define DIM     1024
#define NSTATE  64
#define NFIELD  256                      // per (t,b): [k_norm|v|q|g] x 64
#define PROJ_TSTRIDE (BATCH * NFIELD)    // 4096 floats per t
static constexpr float EPS = 1e-6f;

// ============================ projection GEMM ============================
// (unchanged from R2 — L2-traffic-fixed tiled fp32 GEMM, ~345 us)

#define BM   64
#define BK   16
#define APAD 68
#define BPAD 260

__global__ __launch_bounds__(256, 2) void proj_kernel(
    const float* __restrict__ x,
    const float* __restrict__ Wk, const float* __restrict__ Wv,
    const float* __restrict__ Wq, const float* __restrict__ Wb,
    const float* __restrict__ bb,
    float* __restrict__ proj)
{
    __shared__ float As[BK][APAD];
    __shared__ float Bs[BK][BPAD];

    const int tid = threadIdx.x;
    const int tx = tid & 15, ty = tid >> 4;
    const int ms = tid >> 2;
    const int js = tid & 3;
    const size_t mbase = (size_t)blockIdx.x * BM;
    const float* xrow = x + (mbase + ms) * DIM;
    const int nf = tid >> 6, n63 = tid & 63;
    const float* Wrow = (nf == 0 ? Wk : nf == 1 ? Wv : nf == 2 ? Wq : Wb)
                        + (size_t)n63 * DIM;

    float acc[4][16] = {};

    float4 xa = *(const float4*)(xrow + 4 * js);
    float4 w0 = *(const float4*)(Wrow + 0);
    float4 w1 = *(const float4*)(Wrow + 4);
    float4 w2 = *(const float4*)(Wrow + 8);
    float4 w3 = *(const float4*)(Wrow + 12);

    for (int k0 = 0; k0 < DIM; k0 += BK) {
        __syncthreads();
        As[4 * js + 0][ms] = xa.x;
        As[4 * js + 1][ms] = xa.y;
        As[4 * js + 2][ms] = xa.z;
        As[4 * js + 3][ms] = xa.w;
        Bs[ 0][tid] = w0.x; Bs[ 1][tid] = w0.y; Bs[ 2][tid] = w0.z; Bs[ 3][tid] = w0.w;
        Bs[ 4][tid] = w1.x; Bs[ 5][tid] = w1.y; Bs[ 6][tid] = w1.z; Bs[ 7][tid] = w1.w;
        Bs[ 8][tid] = w2.x; Bs[ 9][tid] = w2.y; Bs[10][tid] = w2.z; Bs[11][tid] = w2.w;
        Bs[12][tid] = w3.x; Bs[13][tid] = w3.y; Bs[14][tid] = w3.z; Bs[15][tid] = w3.w;
        __syncthreads();

        if (k0 + BK < DIM) {
            const int kn = k0 + BK;
            xa = *(const float4*)(xrow + kn + 4 * js);
            w0 = *(const float4*)(Wrow + kn + 0);
            w1 = *(const float4*)(Wrow + kn + 4);
            w2 = *(const float4*)(Wrow + kn + 8);
            w3 = *(const float4*)(Wrow + kn + 12);
        }

        #pragma unroll
        for (int k = 0; k < BK; ++k) {
            float a[4];
            { float4 t = *(const float4*)(&As[k][ty * 4]);
              a[0] = t.x; a[1] = t.y; a[2] = t.z; a[3] = t.w; }
            float bfr[16];
            #pragma unroll
            for (int w = 0; w < 4; ++w) {
                float4 t = *(const float4*)(&Bs[k][64 * w + 4 * tx]);
                bfr[4 * w + 0] = t.x; bfr[4 * w + 1] = t.y;
                bfr[4 * w + 2] = t.z; bfr[4 * w + 3] = t.w;
            }
            #pragma unroll
            for (int mm = 0; mm < 4; ++mm)
                #pragma unroll
                for (int nn = 0; nn < 16; ++nn)
                    acc[mm][nn] = fmaf(a[mm], bfr[nn], acc[mm][nn]);
        }
    }

    #pragma unroll
    for (int mm = 0; mm < 4; ++mm) {
        float s = acc[mm][0] * acc[mm][0] + acc[mm][1] * acc[mm][1]
                + acc[mm][2] * acc[mm][2] + acc[mm][3] * acc[mm][3];
        s += __shfl_xor(s, 1); s += __shfl_xor(s, 2);
        s += __shfl_xor(s, 4); s += __shfl_xor(s, 8);
        const float sc = 1.f / (sqrtf(s) + EPS);
        acc[mm][0] *= sc; acc[mm][1] *= sc; acc[mm][2] *= sc; acc[mm][3] *= sc;
    }
    const float bb0 = bb[4 * tx + 0], bb1 = bb[4 * tx + 1];
    const float bb2 = bb[4 * tx + 2], bb3 = bb[4 * tx + 3];
    #pragma unroll
    for (int mm = 0; mm < 4; ++mm) {
        acc[mm][12] = 1.f / (1.f + __expf(-(acc[mm][12] + bb0)));
        acc[mm][13] = 1.f / (1.f + __expf(-(acc[mm][13] + bb1)));
        acc[mm][14] = 1.f / (1.f + __expf(-(acc[mm][14] + bb2)));
        acc[mm][15] = 1.f / (1.f + __expf(-(acc[mm][15] + bb3)));
    }
    #pragma unroll
    for (int mm = 0; mm < 4; ++mm) {
        float* dst = proj + (mbase + ty * 4 + mm) * NFIELD;
        *(float4*)(dst +   0 + 4 * tx) = make_float4(acc[mm][ 0], acc[mm][ 1], acc[mm][ 2], acc[mm][ 3]);
        *(float4*)(dst +  64 + 4 * tx) = make_float4(acc[mm][ 4], acc[mm][ 5], acc[mm][ 6], acc[mm][ 7]);
        *(float4*)(dst + 128 + 4 * tx) = make_float4(acc[mm][ 8], acc[mm][ 9], acc[mm][10], acc[mm][11]);
        *(float4*)(dst + 192 + 4 * tx) = make_float4(acc[mm][12], acc[mm][13], acc[mm][14], acc[mm][15]);
    }
}

// ============================ sequential scan v4 ============================
// Lookahead reassociation: carry a_t = S_{t-1}.kn_t.
//   d_t = v_t - a_t                      (chain: sub)
//   S_t = g_t*S_{t-1} + d_t*kn_t        (chain: 1 fma, off the a-chain)
//   a_{t+1} = g_t*b_t + d_t*c_t         (chain: 1 fma)
//     b_t = S_{t-1}.kn_{t+1}  -- fresh dot off S (1.5 steps of slack)
//     c_t = kn_t.kn_{t+1}     -- state-independent, in-step from registers
// Reduces are now leaves, not links. silu deferred to a post-kernel.

template <int CTRL>
__device__ __forceinline__ float dpp_add(float x) {
    int yi = __builtin_amdgcn_update_dpp(0, __float_as_int(x), CTRL, 0xF, 0xF, true);
    return x + __int_as_float(yi);
}
__device__ __forceinline__ float reduce16(float x) {
    x = dpp_add<0x121>(x);   // row_ror:1
    x = dpp_add<0x122>(x);   // row_ror:2
    x = dpp_add<0x124>(x);   // row_ror:4
    x = dpp_add<0x128>(x);   // row_ror:8
    return x;
}
__device__ __forceinline__ float dot4r(const float4& u, const float4& w) {
    float t0 = u.x * w.x; t0 = fmaf(u.y, w.y, t0);
    float t1 = u.z * w.z; t1 = fmaf(u.w, w.w, t1);
    return reduce16(t0 + t1);
}

#define CH 64
#define NCHUNK (T_STEPS / CH)

__global__ __launch_bounds__(128) void scan_kernel(
    const float* __restrict__ proj,  // [T][B][256]
    const float* __restrict__ S0,    // [B][64][64]
    float* __restrict__ out,         // [T][B][64]  (raw Sq; silu applied later)
    float* __restrict__ Sfin)        // [B][64][64]
{
    __shared__ float KQ[2][CH][128];   // [s][0:64)=kn, [64:128)=q
    __shared__ float VG[2][CH][16];    // [s][0:8)=v rows, [8:16)=g

    const int tid = threadIdx.x;          // 0..127
    const int l   = tid & 15;
    const int grp = tid >> 4;             // 0..7
    const int b   = blockIdx.x >> 3;
    const int i0  = (blockIdx.x & 7) * 8;
    const int i   = i0 + grp;
    const int c0  = l * 4;

    const size_t srow = ((size_t)(b * 64 + i)) * 64 + c0;
    float4 S = *(const float4*)(S0 + srow);

    const float* pb = proj + (size_t)b * NFIELD;

    const int s_kq = tid >> 5;
    const int fraw = (tid * 4) & 127;
    const int fmap = (fraw < 64) ? fraw : fraw + 64;
    const int svg0 = tid >> 2;
    const int rvg  = (tid & 3) * 4;
    const int fvg  = (rvg < 8) ? (64 + i0 + rvg) : (192 + i0 + rvg - 8);

    float4 hold[18];

    auto load_chunk = [&](int c) {
        const float* cbase = pb + (size_t)c * CH * PROJ_TSTRIDE;
        #pragma unroll
        for (int it = 0; it < 16; ++it)
            hold[it] = *(const float4*)(cbase + (size_t)(it * 4 + s_kq) * PROJ_TSTRIDE + fmap);
        #pragma unroll
        for (int it = 0; it < 2; ++it)
            hold[16 + it] = *(const float4*)(cbase + (size_t)(it * 32 + svg0) * PROJ_TSTRIDE + fvg);
    };
    auto store_chunk = [&](int nb) {
        #pragma unroll
        for (int it = 0; it < 16; ++it)
            *(float4*)(&KQ[nb][it * 4 + s_kq][fraw]) = hold[it];
        #pragma unroll
        for (int it = 0; it < 2; ++it)
            *(float4*)(&VG[nb][it * 32 + svg0][rvg]) = hold[16 + it];
    };

    load_chunk(0);
    store_chunk(0);
    __syncthreads();

    float4 knA, knB_s[3], q_s[3];
    float  v_s[3], g_s[3];
    float  a;

    auto prime = [&](int nb) {
        knA = *(const float4*)(&KQ[nb][0][c0]);
        a = dot4r(S, knA);                    // a = S.kn[first step of chunk]
        #pragma unroll
        for (int j = 0; j < 2; ++j) {
            knB_s[j] = *(const float4*)(&KQ[nb][j + 1][c0]);
            q_s[j]   = *(const float4*)(&KQ[nb][j][64 + c0]);
            v_s[j]   = VG[nb][j][grp];
            g_s[j]   = VG[nb][j][8 + grp];
        }
    };
    prime(0);

    float osel = 0.f;

    for (int c = 0; c < NCHUNK; ++c) {
        const int cb = c & 1;
        const bool more = (c + 1 < NCHUNK);
        if (more) load_chunk(c + 1);

        #pragma unroll
        for (int s = 0; s < CH; ++s) {
            const int j  = s % 3;
            const int jn = (s + 2) % 3;
            if (s + 2 < CH) {                 // LDS prefetch, 2 steps ahead
                q_s[jn] = *(const float4*)(&KQ[cb][s + 2][64 + c0]);
                v_s[jn] = VG[cb][s + 2][grp];
                g_s[jn] = VG[cb][s + 2][8 + grp];
                knB_s[jn] = (s + 3 < CH)
                    ? *(const float4*)(&KQ[cb][s + 3][c0])
                    : make_float4(0.f, 0.f, 0.f, 0.f);
            }
            const float4 knB = knB_s[j], q = q_s[j];
            const float  v = v_s[j], g = g_s[j];

            const float d = v - a;

            float cc = 0.f, bb2 = 0.f;
            if (s < CH - 1) {                 // b_t, c_t off the carried chain
                cc  = dot4r(knA, knB);
                bb2 = dot4r(S, knB);          // uses S_{t-1} (pre-update)
            }

            S.x = fmaf(d, knA.x, g * S.x);
            S.y = fmaf(d, knA.y, g * S.y);
            S.z = fmaf(d, knA.z, g * S.z);
            S.w = fmaf(d, knA.w, g * S.w);

            if (s < CH - 1) a = fmaf(d, cc, g * bb2);

            const float sq = dot4r(S, q);
            osel = ((s & 15) == l) ? sq : osel;
            if ((s & 15) == 15) {
                const int tbase = c * CH + (s - 15);
                out[((size_t)(tbase + l) * BATCH + b) * 64 + i] = osel;
            }
            knA = knB;
        }

        if (more) {
            const int nb = (c + 1) & 1;
            store_chunk(nb);
            __syncthreads();
            prime(nb);                        // boundary: a recomputed from S
        }
    }

    *(float4*)(Sfin + srow) = S;
}

// ============================ silu post-kernel ============================
// out holds raw Sq; apply y = x*x*sigmoid(x) elementwise (first T*B*64 only).
__global__ __launch_bounds__(256) void silu_kernel(float* __restrict__ out) {
    const int idx = blockIdx.x * 256 + threadIdx.x;
    float4* p = (float4*)out + idx;
    float4 x = *p;
    x.x = x.x * x.x / (1.f + __expf(-x.x));
    x.y = x.y * x.y / (1.f + __expf(-x.y));
    x.z = x.z * x.z / (1.f + __expf(-x.z));
    x.w = x.w * x.w / (1.f + __expf(-x.w));
    *p = x;
}

// ================================ launch ================================
extern "C" void kernel_launch(void* const* d_in, const int* in_sizes, int n_in,
                              void* d_out, int out_size, void* d_ws, size_t ws_size,
                              hipStream_t stream) {
    const float* x  = (const float*)d_in[0];
    const float* S0 = (const float*)d_in[1];
    const float* Wk = (const float*)d_in[2];
    const float* Wv = (const float*)d_in[3];
    const float* Wq = (const float*)d_in[4];
    const float* Wb = (const float*)d_in[5];
    const float* bb = (const float*)d_in[6];

    float* out  = (float*)d_out;                               // [T][B][64]
    float* Sfin = out + (size_t)T_STEPS * BATCH * NSTATE;      // [B][64][64]
    float* proj = (float*)d_ws;                                // [T*B][256] = 33.5 MB

    proj_kernel<<<(T_STEPS * BATCH) / BM, 256, 0, stream>>>(x, Wk, Wv, Wq, Wb, bb, proj);
    scan_kernel<<<(BATCH * NSTATE) / 8, 128, 0, stream>>>(proj, S0, out, Sfin);
    silu_kernel<<<(T_STEPS * BATCH * NSTATE) / 4 / 256, 256, 0, stream>>>(out);
}

// Round 5
// 549.776 us; speedup vs baseline: 8.8461x; 1.1376x over previous
//
#include <hip/hip_runtime.h>
#include <math.h>

#define T_STEPS 2048
#define BATCH   16
#define DIM     1024
#define NSTATE  64
#define NFIELD  256                      // per (t,b): [k_norm|v|q|g] x 64
#define PROJ_TSTRIDE (BATCH * NFIELD)    // 4096 floats per t
static constexpr float EPS = 1e-6f;

#define AS1 __attribute__((address_space(1)))
#define AS3 __attribute__((address_space(3)))

// ============================ projection GEMM ============================
// (unchanged — L2-traffic-fixed tiled fp32 GEMM, ~345 us)

#define BM   64
#define BK   16
#define APAD 68
#define BPAD 260

__global__ __launch_bounds__(256, 2) void proj_kernel(
    const float* __restrict__ x,
    const float* __restrict__ Wk, const float* __restrict__ Wv,
    const float* __restrict__ Wq, const float* __restrict__ Wb,
    const float* __restrict__ bb,
    float* __restrict__ proj)
{
    __shared__ float As[BK][APAD];
    __shared__ float Bs[BK][BPAD];

    const int tid = threadIdx.x;
    const int tx = tid & 15, ty = tid >> 4;
    const int ms = tid >> 2;
    const int js = tid & 3;
    const size_t mbase = (size_t)blockIdx.x * BM;
    const float* xrow = x + (mbase + ms) * DIM;
    const int nf = tid >> 6, n63 = tid & 63;
    const float* Wrow = (nf == 0 ? Wk : nf == 1 ? Wv : nf == 2 ? Wq : Wb)
                        + (size_t)n63 * DIM;

    float acc[4][16] = {};

    float4 xa = *(const float4*)(xrow + 4 * js);
    float4 w0 = *(const float4*)(Wrow + 0);
    float4 w1 = *(const float4*)(Wrow + 4);
    float4 w2 = *(const float4*)(Wrow + 8);
    float4 w3 = *(const float4*)(Wrow + 12);

    for (int k0 = 0; k0 < DIM; k0 += BK) {
        __syncthreads();
        As[4 * js + 0][ms] = xa.x;
        As[4 * js + 1][ms] = xa.y;
        As[4 * js + 2][ms] = xa.z;
        As[4 * js + 3][ms] = xa.w;
        Bs[ 0][tid] = w0.x; Bs[ 1][tid] = w0.y; Bs[ 2][tid] = w0.z; Bs[ 3][tid] = w0.w;
        Bs[ 4][tid] = w1.x; Bs[ 5][tid] = w1.y; Bs[ 6][tid] = w1.z; Bs[ 7][tid] = w1.w;
        Bs[ 8][tid] = w2.x; Bs[ 9][tid] = w2.y; Bs[10][tid] = w2.z; Bs[11][tid] = w2.w;
        Bs[12][tid] = w3.x; Bs[13][tid] = w3.y; Bs[14][tid] = w3.z; Bs[15][tid] = w3.w;
        __syncthreads();

        if (k0 + BK < DIM) {
            const int kn = k0 + BK;
            xa = *(const float4*)(xrow + kn + 4 * js);
            w0 = *(const float4*)(Wrow + kn + 0);
            w1 = *(const float4*)(Wrow + kn + 4);
            w2 = *(const float4*)(Wrow + kn + 8);
            w3 = *(const float4*)(Wrow + kn + 12);
        }

        #pragma unroll
        for (int k = 0; k < BK; ++k) {
            float a[4];
            { float4 t = *(const float4*)(&As[k][ty * 4]);
              a[0] = t.x; a[1] = t.y; a[2] = t.z; a[3] = t.w; }
            float bfr[16];
            #pragma unroll
            for (int w = 0; w < 4; ++w) {
                float4 t = *(const float4*)(&Bs[k][64 * w + 4 * tx]);
                bfr[4 * w + 0] = t.x; bfr[4 * w + 1] = t.y;
                bfr[4 * w + 2] = t.z; bfr[4 * w + 3] = t.w;
            }
            #pragma unroll
            for (int mm = 0; mm < 4; ++mm)
                #pragma unroll
                for (int nn = 0; nn < 16; ++nn)
                    acc[mm][nn] = fmaf(a[mm], bfr[nn], acc[mm][nn]);
        }
    }

    #pragma unroll
    for (int mm = 0; mm < 4; ++mm) {
        float s = acc[mm][0] * acc[mm][0] + acc[mm][1] * acc[mm][1]
                + acc[mm][2] * acc[mm][2] + acc[mm][3] * acc[mm][3];
        s += __shfl_xor(s, 1); s += __shfl_xor(s, 2);
        s += __shfl_xor(s, 4); s += __shfl_xor(s, 8);
        const float sc = 1.f / (sqrtf(s) + EPS);
        acc[mm][0] *= sc; acc[mm][1] *= sc; acc[mm][2] *= sc; acc[mm][3] *= sc;
    }
    const float bb0 = bb[4 * tx + 0], bb1 = bb[4 * tx + 1];
    const float bb2 = bb[4 * tx + 2], bb3 = bb[4 * tx + 3];
    #pragma unroll
    for (int mm = 0; mm < 4; ++mm) {
        acc[mm][12] = 1.f / (1.f + __expf(-(acc[mm][12] + bb0)));
        acc[mm][13] = 1.f / (1.f + __expf(-(acc[mm][13] + bb1)));
        acc[mm][14] = 1.f / (1.f + __expf(-(acc[mm][14] + bb2)));
        acc[mm][15] = 1.f / (1.f + __expf(-(acc[mm][15] + bb3)));
    }
    #pragma unroll
    for (int mm = 0; mm < 4; ++mm) {
        float* dst = proj + (mbase + ty * 4 + mm) * NFIELD;
        *(float4*)(dst +   0 + 4 * tx) = make_float4(acc[mm][ 0], acc[mm][ 1], acc[mm][ 2], acc[mm][ 3]);
        *(float4*)(dst +  64 + 4 * tx) = make_float4(acc[mm][ 4], acc[mm][ 5], acc[mm][ 6], acc[mm][ 7]);
        *(float4*)(dst + 128 + 4 * tx) = make_float4(acc[mm][ 8], acc[mm][ 9], acc[mm][10], acc[mm][11]);
        *(float4*)(dst + 192 + 4 * tx) = make_float4(acc[mm][12], acc[mm][13], acc[mm][14], acc[mm][15]);
    }
}

// ============================ sequential scan v5 ============================
// Staging: global -> LDS via global_load_lds DMA (no VGPR round trip, no
// hold[] -> ~70 VGPRs freed so the scheduler can honor the prefetch).
// LDS -> reg: depth-4 rotating slots, loads issued 4 steps ahead.
// CH=32 so the unrolled body fits L1I. v,g interleaved -> one ds_read_b64.

template <int CTRL>
__device__ __forceinline__ float dpp_add(float x) {
    int yi = __builtin_amdgcn_update_dpp(0, __float_as_int(x), CTRL, 0xF, 0xF, true);
    return x + __int_as_float(yi);
}
__device__ __forceinline__ float reduce16(float x) {
    x = dpp_add<0x121>(x);   // row_ror:1
    x = dpp_add<0x122>(x);   // row_ror:2
    x = dpp_add<0x124>(x);   // row_ror:4
    x = dpp_add<0x128>(x);   // row_ror:8
    return x;
}
__device__ __forceinline__ float dot4r(const float4& u, const float4& w) {
    float t0 = u.x * w.x; t0 = fmaf(u.y, w.y, t0);
    float t1 = u.z * w.z; t1 = fmaf(u.w, w.w, t1);
    return reduce16(t0 + t1);
}

#define CH 32
#define NCHUNK (T_STEPS / CH)

__global__ __launch_bounds__(128) void scan_kernel(
    const float* __restrict__ proj,  // [T][B][256]
    const float* __restrict__ S0,    // [B][64][64]
    float* __restrict__ out,         // [T][B][64]  (raw Sq; silu applied later)
    float* __restrict__ Sfin)        // [B][64][64]
{
    __shared__ float KQ[2][CH][128];   // [s][0:64)=kn, [64:128)=q   (32 KB)
    __shared__ float VG[2][CH][16];    // [s][2r]=v(i0+r), [s][2r+1]=g(i0+r)

    const int tid = threadIdx.x;          // 0..127
    const int l   = tid & 15;
    const int grp = tid >> 4;             // 0..7 -> row within block
    const int b   = blockIdx.x >> 3;
    const int i0  = (blockIdx.x & 7) * 8;
    const int i   = i0 + grp;
    const int c0  = l * 4;

    const size_t srow = ((size_t)(b * 64 + i)) * 64 + c0;
    float4 S = *(const float4*)(S0 + srow);

    const float* pb = proj + (size_t)b * NFIELD;
    const int wid = tid >> 6, wl = tid & 63;

    // --- DMA address maps (constant per lane) ---
    // KQ chunk = CH*512B; inst n covers 1024B: lds = n*1024 + wl*16
    //   s = 2n + (wl>>5), proj field = (wl&31)*4 (+64 shift into q for wl&31>=16)
    const int l31  = wl & 31;
    const int kq_f = l31 * 4 + ((l31 >= 16) ? 64 : 0);
    const int kq_s = wl >> 5;
    // VG chunk = CH*64B; inst p covers 256B (size=4): lds = p*256 + wl*4
    //   s = 4p + (wl>>4), idx = wl&15 -> field v:64+i0+idx/2 | g:192+i0+idx/2
    const int idx  = wl & 15;
    const int vg_f = (idx & 1) ? (192 + i0 + (idx >> 1)) : (64 + i0 + (idx >> 1));
    const int vg_s = wl >> 4;

    auto stage = [&](int c, int nb) {
        const float* cbase = pb + (size_t)c * CH * PROJ_TSTRIDE;
        #pragma unroll
        for (int m = 0; m < 8; ++m) {                    // 16 KQ insts over 2 waves
            const int n = wid * 8 + m;
            const float* g = cbase + (size_t)(2 * n + kq_s) * PROJ_TSTRIDE + kq_f;
            void* lp = (char*)&KQ[nb][0][0] + n * 1024;
            __builtin_amdgcn_global_load_lds((const AS1 void*)g, (AS3 void*)lp, 16, 0, 0);
        }
        #pragma unroll
        for (int m = 0; m < 4; ++m) {                    // 8 VG insts over 2 waves
            const int p = wid * 4 + m;
            const float* g = cbase + (size_t)(4 * p + vg_s) * PROJ_TSTRIDE + vg_f;
            void* lp = (char*)&VG[nb][0][0] + p * 256;
            __builtin_amdgcn_global_load_lds((const AS1 void*)g, (AS3 void*)lp, 4, 0, 0);
        }
    };

    float4 kn_s[4], q_s[4];
    float2 vg_s4[4];
    auto ldslot = [&](int cb, int s, int j) {
        kn_s[j]  = *(const float4*)(&KQ[cb][s][c0]);
        q_s[j]   = *(const float4*)(&KQ[cb][s][64 + c0]);
        vg_s4[j] = *(const float2*)(&VG[cb][s][2 * grp]);
    };

    stage(0, 0);
    __syncthreads();                     // waits DMA (vmcnt) + all threads

    float a;
    auto prime = [&](int nb) {
        #pragma unroll
        for (int j = 0; j < 4; ++j) ldslot(nb, j, j);
        a = dot4r(S, kn_s[0]);           // recompute carried dot from S
    };
    prime(0);

    float osel = 0.f;

    for (int c = 0; c < NCHUNK; ++c) {
        const int cb = c & 1;
        const bool more = (c + 1 < NCHUNK);
        if (more) stage(c + 1, cb ^ 1);  // DMA in flight across this chunk

        #pragma unroll
        for (int s = 0; s < CH; ++s) {
            const int j = s & 3;
            const float4 kn = kn_s[j], q = q_s[j];
            const float  v = vg_s4[j].x, g = vg_s4[j].y;

            if (s + 4 < CH) ldslot(cb, s + 4, j);   // refill the slot just freed

            const float d = v - a;
            S.x = fmaf(d, kn.x, g * S.x);
            S.y = fmaf(d, kn.y, g * S.y);
            S.z = fmaf(d, kn.z, g * S.z);
            S.w = fmaf(d, kn.w, g * S.w);

            const float sq = dot4r(S, q);
            if (s + 1 < CH) a = dot4r(S, kn_s[(s + 1) & 3]);

            osel = ((s & 15) == l) ? sq : osel;
            if ((s & 15) == 15) {
                const int tbase = c * CH + (s - 15);
                out[((size_t)(tbase + l) * BATCH + b) * 64 + i] = osel;
            }
        }

        if (more) {
            __syncthreads();             // next chunk's DMA complete
            prime(cb ^ 1);
        }
    }

    *(float4*)(Sfin + srow) = S;
}

// ============================ silu post-kernel ============================
__global__ __launch_bounds__(256) void silu_kernel(float* __restrict__ out) {
    const int idx = blockIdx.x * 256 + threadIdx.x;
    float4* p = (float4*)out + idx;
    float4 x = *p;
    x.x = x.x * x.x / (1.f + __expf(-x.x));
    x.y = x.y * x.y / (1.f + __expf(-x.y));
    x.z = x.z * x.z / (1.f + __expf(-x.z));
    x.w = x.w * x.w / (1.f + __expf(-x.w));
    *p = x;
}

// ================================ launch ================================
extern "C" void kernel_launch(void* const* d_in, const int* in_sizes, int n_in,
                              void* d_out, int out_size, void* d_ws, size_t ws_size,
                              hipStream_t stream) {
    const float* x  = (const float*)d_in[0];
    const float* S0 = (const float*)d_in[1];
    const float* Wk = (const float*)d_in[2];
    const float* Wv = (const float*)d_in[3];
    const float* Wq = (const float*)d_in[4];
    const float* Wb = (const float*)d_in[5];
    const float* bb = (const float*)d_in[6];

    float* out  = (float*)d_out;                               // [T][B][64]
    float* Sfin = out + (size_t)T_STEPS * BATCH * NSTATE;      // [B][64][64]
    float* proj = (float*)d_ws;                                // [T*B][256] = 33.5 MB

    proj_kernel<<<(T_STEPS * BATCH) / BM, 256, 0, stream>>>(x, Wk, Wv, Wq, Wb, bb, proj);
    scan_kernel<<<(BATCH * NSTATE) / 8, 128, 0, stream>>>(proj, S0, out, Sfin);
    silu_kernel<<<(T_STEPS * BATCH * NSTATE) / 4 / 256, 256, 0, stream>>>(out);
}